// Round 1
// baseline (77.817 us; speedup 1.0000x reference)
//
#include <hip/hip_runtime.h>

#define NB 8       // batch
#define TAPS 5     // K/2
#define PADN 2     // (K-2)/4

__device__ __forceinline__ float4 ld4(const float* p) {
    return *reinterpret_cast<const float4*>(p);
}

// antireflect ("odd reflect") row load: row m in [-2, N+1], 4 cols at `col`
__device__ __forceinline__ float4 padrow4(const float* __restrict__ plane, int m, int N, int col) {
    if ((unsigned)m < (unsigned)N) return ld4(plane + (size_t)m * N + col);
    const int er = (m < 0) ? 0 : (N - 1);
    const int rr = (m < 0) ? -m : (2 * (N - 1) - m);
    float4 e = ld4(plane + (size_t)er * N + col);
    float4 r = ld4(plane + (size_t)rr * N + col);
    return make_float4(2.f * e.x - r.x, 2.f * e.y - r.y, 2.f * e.z - r.z, 2.f * e.w - r.w);
}

// Vertical synthesis: S[b, 2n+p, c] = sum_t hk[p,t]*Apad[n+t-2, c] + gk[p,t]*Bpad[n+t-2, c]
// (A,Bc) = (ss, sd) -> S ; (C,E) = (ds, dd) -> D. Inputs [NB, N, N], outputs [NB, 2N, N].
__global__ void idwt_vert(const float* __restrict__ Aa, const float* __restrict__ Ab,
                          const float* __restrict__ Ac, const float* __restrict__ Ad,
                          const float* __restrict__ h, const float* __restrict__ g,
                          float* __restrict__ So, float* __restrict__ Do, int N) {
    const int Nv = N >> 2;
    const int total = NB * 2 * N * Nv;
    int tid = blockIdx.x * blockDim.x + threadIdx.x;
    if (tid >= total) return;
    const int col = (tid % Nv) << 2;
    int rest = tid / Nv;
    const int r = rest % (2 * N);
    const int b = rest / (2 * N);
    const int n = r >> 1, p = r & 1;

    float hk[TAPS], gk[TAPS];
#pragma unroll
    for (int t = 0; t < TAPS; ++t) {
        hk[t] = h[8 - 2 * t + p];   // hk[p][t] = h[8-2t+p]
        gk[t] = g[8 - 2 * t + p];
    }

    const size_t plane = (size_t)N * N;
    const float* a  = Aa + (size_t)b * plane;
    const float* bb = Ab + (size_t)b * plane;
    const float* c  = Ac + (size_t)b * plane;
    const float* d  = Ad + (size_t)b * plane;

    float4 aS = make_float4(0.f, 0.f, 0.f, 0.f);
    float4 aD = make_float4(0.f, 0.f, 0.f, 0.f);
#pragma unroll
    for (int t = 0; t < TAPS; ++t) {
        const int m = n + t - PADN;
        float4 va = padrow4(a,  m, N, col);
        float4 vb = padrow4(bb, m, N, col);
        float4 vc = padrow4(c,  m, N, col);
        float4 vd = padrow4(d,  m, N, col);
        aS.x += hk[t] * va.x + gk[t] * vb.x;
        aS.y += hk[t] * va.y + gk[t] * vb.y;
        aS.z += hk[t] * va.z + gk[t] * vb.z;
        aS.w += hk[t] * va.w + gk[t] * vb.w;
        aD.x += hk[t] * vc.x + gk[t] * vd.x;
        aD.y += hk[t] * vc.y + gk[t] * vd.y;
        aD.z += hk[t] * vc.z + gk[t] * vd.z;
        aD.w += hk[t] * vc.w + gk[t] * vd.w;
    }
    const size_t o = ((size_t)b * 2 * N + r) * N + col;
    *reinterpret_cast<float4*>(So + o) = aS;
    *reinterpret_cast<float4*>(Do + o) = aD;
}

// Horizontal synthesis: out[b, row, 2c+q] = sum_t hk[q,t]*Spad[row, c+t-2] + gk[q,t]*Dpad[row, c+t-2]
// S,D: [NB, M, N]; out: [NB, M, 2N]
__global__ void idwt_horz(const float* __restrict__ S, const float* __restrict__ D,
                          const float* __restrict__ h, const float* __restrict__ g,
                          float* __restrict__ out, int M, int N) {
    const int total = NB * M * N;
    int tid = blockIdx.x * blockDim.x + threadIdx.x;
    if (tid >= total) return;
    const int c = tid % N;
    int rest = tid / N;
    const int row = rest % M;
    const int b = rest / M;

    const float* srow = S + ((size_t)b * M + row) * N;
    const float* drow = D + ((size_t)b * M + row) * N;

    float sv[TAPS], dv[TAPS];
#pragma unroll
    for (int t = 0; t < TAPS; ++t) {
        const int j = c + t - PADN;
        if ((unsigned)j < (unsigned)N) {
            sv[t] = srow[j];
            dv[t] = drow[j];
        } else {
            const int er = (j < 0) ? 0 : (N - 1);
            const int rr = (j < 0) ? -j : (2 * (N - 1) - j);
            sv[t] = 2.f * srow[er] - srow[rr];
            dv[t] = 2.f * drow[er] - drow[rr];
        }
    }

    float2 o = make_float2(0.f, 0.f);
#pragma unroll
    for (int t = 0; t < TAPS; ++t) {
        o.x += h[8 - 2 * t] * sv[t] + g[8 - 2 * t] * dv[t];
        o.y += h[9 - 2 * t] * sv[t] + g[9 - 2 * t] * dv[t];
    }
    *reinterpret_cast<float2*>(out + (((size_t)b * M + row) * 2 * N) + 2 * c) = o;
}

extern "C" void kernel_launch(void* const* d_in, const int* in_sizes, int n_in,
                              void* d_out, int out_size, void* d_ws, size_t ws_size,
                              hipStream_t stream) {
    const float* ss = (const float*)d_in[0];
    const float* sd[3] = {(const float*)d_in[1], (const float*)d_in[2], (const float*)d_in[3]};
    const float* ds[3] = {(const float*)d_in[4], (const float*)d_in[5], (const float*)d_in[6]};
    const float* dd[3] = {(const float*)d_in[7], (const float*)d_in[8], (const float*)d_in[9]};
    const float* h = (const float*)d_in[10];
    const float* g = (const float*)d_in[11];
    float* out = (float*)d_out;

    // ws layout: I (inter-level, 8 MiB) | S (16 MiB) | D (16 MiB) = 40 MiB total
    char* ws = (char*)d_ws;
    float* I = (float*)ws;
    float* S = (float*)(ws + ((size_t)8 << 20));
    float* D = (float*)(ws + ((size_t)24 << 20));

    const int threads = 256;
    auto run_level = [&](const float* a, const float* sdp, const float* dsp, const float* ddp,
                         float* dst, int N) {
        const int totV = NB * 2 * N * (N >> 2);
        idwt_vert<<<(totV + threads - 1) / threads, threads, 0, stream>>>(
            a, sdp, dsp, ddp, h, g, S, D, N);
        const int M = 2 * N;
        const int totH = NB * M * N;
        idwt_horz<<<(totH + threads - 1) / threads, threads, 0, stream>>>(
            S, D, h, g, dst, M, N);
    };

    run_level(ss, sd[2], ds[2], dd[2], I, 128);   // level 2: 128 -> 256 (into I)
    run_level(I,  sd[1], ds[1], dd[1], I, 256);   // level 1: 256 -> 512 (into I; input consumed first)
    run_level(I,  sd[0], ds[0], dd[0], out, 512); // level 0: 512 -> 1024 (into d_out)
}